// Round 11
// baseline (335.575 us; speedup 1.0000x reference)
//
#include <hip/hip_runtime.h>
#include <stdint.h>
#include <stddef.h>

#define N_NODES 100000
#define N_EDGES 1600000
#define IN_CH 128
#define HID_CH 128
#define OUT_CH 40

#define NB 196            // buckets: b = dst >> 9 (512 nodes each)
#define GCAP 10240        // per-bucket capacity (mean 8163 + 22 sigma)
#define TILE_EDGES 2048   // edges per WG in bucket_edges
#define LCAP 40           // LDS slots per bucket per tile (mean 10.4 + 9 sigma; slow-path fallback)

#define N_MASK_WORDS 400000   // 100000*128/32
#define N_CVT4 3200000        // 100000*128/4

typedef __attribute__((ext_vector_type(8))) short bf16x8;
typedef __attribute__((ext_vector_type(8))) unsigned short u16x8;
typedef __attribute__((ext_vector_type(4))) float f32x4;

// ---------------- bf16 helpers ----------------
__device__ __forceinline__ ushort f2bf(float f) {
    uint32_t u = __float_as_uint(f);
    uint32_t r = (u + 0x7FFFu + ((u >> 16) & 1u)) >> 16;   // RNE
    return (ushort)r;
}
__device__ __forceinline__ float bf2f(ushort u) {
    return __uint_as_float(((uint32_t)u) << 16);
}

// ---------------- threefry2x32 (JAX PRNG, key = (0,42)) ----------------
__device__ __forceinline__ uint32_t rotl32(uint32_t x, int r) {
    return (x << r) | (x >> (32 - r));
}

__device__ __forceinline__ void threefry2x32_k42(uint32_t x0, uint32_t x1,
                                                 uint32_t& o0, uint32_t& o1) {
    const uint32_t ks0 = 0u, ks1 = 42u;
    const uint32_t ks2 = 0u ^ 42u ^ 0x1BD11BDAu;
    x0 += ks0; x1 += ks1;
    x0 += x1; x1 = rotl32(x1, 13); x1 ^= x0;
    x0 += x1; x1 = rotl32(x1, 15); x1 ^= x0;
    x0 += x1; x1 = rotl32(x1, 26); x1 ^= x0;
    x0 += x1; x1 = rotl32(x1,  6); x1 ^= x0;
    x0 += ks1; x1 += ks2 + 1u;
    x0 += x1; x1 = rotl32(x1, 17); x1 ^= x0;
    x0 += x1; x1 = rotl32(x1, 29); x1 ^= x0;
    x0 += x1; x1 = rotl32(x1, 16); x1 ^= x0;
    x0 += x1; x1 = rotl32(x1, 24); x1 ^= x0;
    x0 += ks2; x1 += ks0 + 2u;
    x0 += x1; x1 = rotl32(x1, 13); x1 ^= x0;
    x0 += x1; x1 = rotl32(x1, 15); x1 ^= x0;
    x0 += x1; x1 = rotl32(x1, 26); x1 ^= x0;
    x0 += x1; x1 = rotl32(x1,  6); x1 ^= x0;
    x0 += ks0; x1 += ks1 + 3u;
    x0 += x1; x1 = rotl32(x1, 17); x1 ^= x0;
    x0 += x1; x1 = rotl32(x1, 29); x1 ^= x0;
    x0 += x1; x1 = rotl32(x1, 16); x1 ^= x0;
    x0 += x1; x1 = rotl32(x1, 24); x1 ^= x0;
    x0 += ks1; x1 += ks2 + 4u;
    x0 += x1; x1 = rotl32(x1, 13); x1 ^= x0;
    x0 += x1; x1 = rotl32(x1, 15); x1 ^= x0;
    x0 += x1; x1 = rotl32(x1, 26); x1 ^= x0;
    x0 += x1; x1 = rotl32(x1,  6); x1 ^= x0;
    x0 += ks2; x1 += ks0 + 5u;
    o0 = x0; o1 = x1;
}

// ---------------- edge load ----------------
__device__ __forceinline__ void load_edge(const void* ei, bool is32, int e,
                                          int& s, int& d) {
    if (is32) {
        const int* p = (const int*)ei;
        s = p[e]; d = p[N_EDGES + e];
    } else {
        const long long* p = (const long long*)ei;
        s = (int)p[e]; d = (int)p[N_EDGES + e];
    }
}

// ---------------- prep: sampled dtype detect (block 0) + zero gcnt (block 1) --------
__global__ __launch_bounds__(256) void prep(const int* __restrict__ ei32,
                                            int* __restrict__ flag,
                                            int* __restrict__ gcnt) {
    const int t = threadIdx.x;
    if (blockIdx.x == 0) {
        __shared__ int red[256];
        int local = 0;
        #pragma unroll
        for (int j = 0; j < 64; ++j) {
            int k = (t * 64 + j) * 97;           // max 1,589,151 < N_EDGES
            local |= ei32[2 * k + 1];
        }
        red[t] = local;
        __syncthreads();
        for (int off = 128; off; off >>= 1) {
            if (t < off) red[t] |= red[t + off];
            __syncthreads();
        }
        if (t == 0) *flag = (red[0] != 0);
    } else {
        for (int i = t; i < NB * 16; i += 256) gcnt[i] = 0;
    }
}

// ---------------- bucketed CSR build, pass 1: LDS-staged append ----------------
__global__ __launch_bounds__(256) void bucket_edges(
    const void* __restrict__ ei, const int* __restrict__ flag,
    int* __restrict__ gcnt, uint2* __restrict__ gbuf) {
    __shared__ uint2 lbuf[NB][LCAP];   // 62.7 KB
    __shared__ int lcnt[NB];
    const bool is32 = (*flag != 0);
    const int t = threadIdx.x;
    for (int b = t; b < NB; b += 256) lcnt[b] = 0;
    __syncthreads();
    const int base = blockIdx.x * TILE_EDGES;
    #pragma unroll
    for (int j = 0; j < TILE_EDGES / 256; ++j) {
        int e = base + j * 256 + t;
        if (e < N_EDGES) {
            int s, d;
            load_edge(ei, is32, e, s, d);
            int b = d >> 9;
            int pos = atomicAdd(&lcnt[b], 1);
            if (pos < LCAP) {
                lbuf[b][pos] = make_uint2((uint32_t)s, (uint32_t)d);
            } else {   // overflow slow path (statistically ~never; correctness-preserving)
                int gp = atomicAdd(&gcnt[b * 16], 1);
                gbuf[(size_t)b * GCAP + gp] = make_uint2((uint32_t)s, (uint32_t)d);
            }
        }
    }
    __syncthreads();
    if (t < NB) {
        int cnt = lcnt[t];
        if (cnt > LCAP) cnt = LCAP;
        if (cnt > 0) {
            int gp = atomicAdd(&gcnt[t * 16], cnt);
            uint2* dst = gbuf + (size_t)t * GCAP + gp;
            for (int i = 0; i < cnt; ++i) dst[i] = lbuf[t][i];
        }
    }
}

// exclusive scan of bucket totals (196 values, 1 block)
__global__ void bucket_scan(const int* __restrict__ gcnt, int* __restrict__ bbase) {
    __shared__ int s[256];
    int t = threadIdx.x;
    int tot = (t < NB) ? gcnt[t * 16] : 0;
    s[t] = tot;
    __syncthreads();
    for (int off = 1; off < 256; off <<= 1) {
        int a = (t >= off) ? s[t - off] : 0;
        __syncthreads();
        s[t] += a;
        __syncthreads();
    }
    if (t < NB) bbase[t] = s[t] - tot;   // exclusive
}

// pass 2: one WG per bucket -> exact degrees (histogram), scan, cursor, place.
__global__ __launch_bounds__(256) void build_csr(
    const int* __restrict__ gcnt, const uint2* __restrict__ gbuf,
    const int* __restrict__ bbase, int* __restrict__ csr, int* __restrict__ cursor) {
    __shared__ int hist[512];
    __shared__ int excl[512];
    __shared__ int cur[512];
    __shared__ int psum[256];
    const int b = blockIdx.x;
    const int t = threadIdx.x;
    hist[t] = 0; hist[t + 256] = 0;
    __syncthreads();
    const int base = bbase[b];
    const int cnt = gcnt[b * 16];
    const uint2* src = gbuf + (size_t)b * GCAP;
    for (int i = t; i < cnt; i += 256)
        atomicAdd(&hist[src[i].y & 511], 1);
    __syncthreads();
    int h0 = hist[2 * t], h1 = hist[2 * t + 1];
    psum[t] = h0 + h1;
    __syncthreads();
    int v = psum[t];
    for (int off = 1; off < 256; off <<= 1) {
        int a = (t >= off) ? psum[t - off] : 0;
        __syncthreads();
        psum[t] += a;
        __syncthreads();
    }
    int pex = psum[t] - v;
    excl[2 * t] = pex;
    excl[2 * t + 1] = pex + h0;
    cur[2 * t] = pex;
    cur[2 * t + 1] = pex + h0;
    __syncthreads();
    for (int j = t; j < 512; j += 256) {
        int node = b * 512 + j;
        if (node < N_NODES) cursor[node] = base + excl[j] + hist[j];
    }
    for (int i = t; i < cnt; i += 256) {
        uint2 p = src[i];
        int pos = atomicAdd(&cur[p.y & 511], 1);
        csr[base + pos] = (int)p.x;
    }
}

// ---------------- fused: x -> bf16 conversion + dropout mask precompute ----------------
__global__ __launch_bounds__(256) void cvt_and_mask(
    const float* __restrict__ in, ushort* __restrict__ out,
    uint32_t* __restrict__ mask) {
    const long gid = (long)blockIdx.x * blockDim.x + threadIdx.x;
    const long stride = (long)gridDim.x * blockDim.x;
    for (long i = gid; i < N_CVT4; i += stride) {
        float4 v = *reinterpret_cast<const float4*>(in + i * 4);
        ushort4 r;
        r.x = f2bf(v.x); r.y = f2bf(v.y); r.z = f2bf(v.z); r.w = f2bf(v.w);
        *reinterpret_cast<ushort4*>(out + i * 4) = r;
    }
    for (long w = gid; w < N_MASK_WORDS; w += stride) {
        uint32_t m = 0;
        #pragma unroll 4
        for (int j = 0; j < 32; ++j) {
            uint32_t o0, o1;
            threefry2x32_k42(0u, (uint32_t)w * 32u + j, o0, o1);
            m |= ((o0 ^ o1) >> 31) << j;
        }
        mask[w] = m;
    }
}

// Weight layout for fast B-frag loads: per col n, per lane-chunk kg (0..3),
// the 8 ks-frags are CONTIGUOUS (128 B per (n,kg)):
//   element (n, k) with ks=k>>5, kg=(k>>3)&3, j=k&7  ->  Wt[n*256 + kg*64 + ks*8 + j]
__global__ void cvt_w2(const float* __restrict__ W1l, const float* __restrict__ W1r,
                       const float* __restrict__ W2l, const float* __restrict__ W2r,
                       ushort* __restrict__ Wt1, ushort* __restrict__ Wt2) {
    int blk = blockIdx.x;
    int k = threadIdx.x;
    int ks = k >> 5, kgp = (k >> 3) & 3, j = k & 7;
    int off = kgp * 64 + ks * 8 + j;
    if (blk < 128) {
        int n = blk;
        float v = (k < 128) ? W1l[(size_t)k * 128 + n] : W1r[(size_t)(k - 128) * 128 + n];
        Wt1[(size_t)n * 256 + off] = f2bf(v);
    } else {
        int n = blk - 128;
        float v = 0.0f;
        if (n < OUT_CH)
            v = (k < 128) ? W2l[(size_t)k * 40 + n] : W2r[(size_t)(k - 128) * 40 + n];
        Wt2[(size_t)n * 256 + off] = f2bf(v);
    }
}

// ---------------- gather-based mean aggregation (bf16, 16B/lane) ----------------
__global__ __launch_bounds__(256) void aggregate_mean_bf(
    const ushort* __restrict__ feat, const int* __restrict__ csr,
    const int* __restrict__ cursor, ushort* __restrict__ out) {
    int node = blockIdx.x * 4 + (threadIdx.x >> 6);
    if (node >= N_NODES) return;
    const int lane = threadIdx.x & 63;
    const int g = lane >> 4;        // 0..3 edge subgroup
    const int c = lane & 15;        // col group: channels c*8..c*8+7
    const int beg = (node > 0) ? cursor[node - 1] : 0;
    const int end = cursor[node];

    float acc[8];
    #pragma unroll
    for (int j = 0; j < 8; ++j) acc[j] = 0.0f;

    int e = beg + g;
    for (; e + 4 < end; e += 8) {
        int s0 = csr[e];
        int s1 = csr[e + 4];
        bf16x8 v0 = *reinterpret_cast<const bf16x8*>(feat + (size_t)s0 * 128 + c * 8);
        bf16x8 v1 = *reinterpret_cast<const bf16x8*>(feat + (size_t)s1 * 128 + c * 8);
        #pragma unroll
        for (int j = 0; j < 8; ++j) acc[j] += bf2f((ushort)v0[j]);
        #pragma unroll
        for (int j = 0; j < 8; ++j) acc[j] += bf2f((ushort)v1[j]);
    }
    if (e < end) {
        int s0 = csr[e];
        bf16x8 v0 = *reinterpret_cast<const bf16x8*>(feat + (size_t)s0 * 128 + c * 8);
        #pragma unroll
        for (int j = 0; j < 8; ++j) acc[j] += bf2f((ushort)v0[j]);
    }

    // sum the 4 edge subgroups (lanes with equal c)
    #pragma unroll
    for (int j = 0; j < 8; ++j) {
        acc[j] += __shfl_xor(acc[j], 16, 64);
        acc[j] += __shfl_xor(acc[j], 32, 64);
    }

    if (g == 0) {
        int deg = end - beg;
        float inv = (deg > 0) ? (1.0f / (float)deg) : 0.0f;
        u16x8 r;
        #pragma unroll
        for (int j = 0; j < 8; ++j) r[j] = f2bf(acc[j] * inv);
        *reinterpret_cast<u16x8*>(out + (size_t)node * 128 + c * 8) = r;
    }
}

// ---------------- layer 1 MFMA: h = dropout(relu([agg|x] @ W1' + b1)) ----------------
// Column-split: each wave computes 16 rows x 64 cols (4 nf-frags).
// colHalf = blockIdx&1 (block pairs sharing A-rows dispatched adjacently ->
// L3 absorbs the 2x A re-read).  12500 waves (~2x R10) with half-length
// B-load chains -> latency-hiding, the binding constraint per R9/R10 evidence.
__global__ __launch_bounds__(256) void layer1_mfma(
    const ushort* __restrict__ agg, const ushort* __restrict__ xbf,
    const ushort* __restrict__ Wt, const float* __restrict__ b1,
    const uint32_t* __restrict__ dmask, ushort* __restrict__ h) {
    const int tid = threadIdx.x;
    const int lane = tid & 63;
    const int l15 = lane & 15, kg = lane >> 4;
    const int colBase = (blockIdx.x & 1) * 64;
    const int wid = (blockIdx.x >> 1) * 4 + (tid >> 6);
    const int row_base = wid * 16;
    if (row_base >= N_NODES) return;   // no barriers below -> safe
    int r0 = row_base + l15;
    int r0c = (r0 < N_NODES) ? r0 : (N_NODES - 1);

    bf16x8 a[8];
    #pragma unroll
    for (int ks = 0; ks < 4; ++ks) {
        a[ks]     = *reinterpret_cast<const bf16x8*>(agg + (size_t)r0c * 128 + ks * 32 + kg * 8);
        a[ks + 4] = *reinterpret_cast<const bf16x8*>(xbf + (size_t)r0c * 128 + ks * 32 + kg * 8);
    }

    f32x4 acc[4];
    #pragma unroll
    for (int nf = 0; nf < 4; ++nf) acc[nf] = (f32x4){0.f, 0.f, 0.f, 0.f};

    #pragma unroll
    for (int nf = 0; nf < 4; ++nf) {
        const ushort* bp = Wt + (size_t)(colBase + nf * 16 + l15) * 256 + kg * 64;
        bf16x8 b0 = *reinterpret_cast<const bf16x8*>(bp + 0);
        bf16x8 b1f = *reinterpret_cast<const bf16x8*>(bp + 8);
        bf16x8 b2f = *reinterpret_cast<const bf16x8*>(bp + 16);
        bf16x8 b3 = *reinterpret_cast<const bf16x8*>(bp + 24);
        bf16x8 b4 = *reinterpret_cast<const bf16x8*>(bp + 32);
        bf16x8 b5 = *reinterpret_cast<const bf16x8*>(bp + 40);
        bf16x8 b6 = *reinterpret_cast<const bf16x8*>(bp + 48);
        bf16x8 b7 = *reinterpret_cast<const bf16x8*>(bp + 56);
        acc[nf] = __builtin_amdgcn_mfma_f32_16x16x32_bf16(a[0], b0, acc[nf], 0, 0, 0);
        acc[nf] = __builtin_amdgcn_mfma_f32_16x16x32_bf16(a[1], b1f, acc[nf], 0, 0, 0);
        acc[nf] = __builtin_amdgcn_mfma_f32_16x16x32_bf16(a[2], b2f, acc[nf], 0, 0, 0);
        acc[nf] = __builtin_amdgcn_mfma_f32_16x16x32_bf16(a[3], b3, acc[nf], 0, 0, 0);
        acc[nf] = __builtin_amdgcn_mfma_f32_16x16x32_bf16(a[4], b4, acc[nf], 0, 0, 0);
        acc[nf] = __builtin_amdgcn_mfma_f32_16x16x32_bf16(a[5], b5, acc[nf], 0, 0, 0);
        acc[nf] = __builtin_amdgcn_mfma_f32_16x16x32_bf16(a[6], b6, acc[nf], 0, 0, 0);
        acc[nf] = __builtin_amdgcn_mfma_f32_16x16x32_bf16(a[7], b7, acc[nf], 0, 0, 0);
    }

    #pragma unroll
    for (int r = 0; r < 4; ++r) {
        int row = row_base + kg * 4 + r;
        if (row < N_NODES) {
            uint4 mw = *reinterpret_cast<const uint4*>(dmask + (size_t)row * 4);
            const uint32_t* mwp = reinterpret_cast<const uint32_t*>(&mw);
            #pragma unroll
            for (int nf = 0; nf < 4; ++nf) {
                int col = colBase + nf * 16 + l15;
                float v = acc[nf][r] + b1[col];
                v = fmaxf(v, 0.0f) * 2.0f;
                if ((mwp[col >> 5] >> (col & 31)) & 1u) v = 0.0f;
                h[(size_t)row * 128 + col] = f2bf(v);
            }
        }
    }
}

// ---------------- layer 2 MFMA: out = log_softmax([agg|h] @ W2' + b2) ----------------
__global__ __launch_bounds__(256) void layer2_mfma(
    const ushort* __restrict__ agg, const ushort* __restrict__ hbf,
    const ushort* __restrict__ Wt2, const float* __restrict__ b2,
    float* __restrict__ out) {
    const int tid = threadIdx.x;
    const int lane = tid & 63;
    const int l15 = lane & 15, kg = lane >> 4;
    const int wid = blockIdx.x * 4 + (tid >> 6);
    const int row_base = wid * 16;
    if (row_base >= N_NODES) return;
    int r0 = row_base + l15;
    int r0c = (r0 < N_NODES) ? r0 : (N_NODES - 1);

    bf16x8 a[8];
    #pragma unroll
    for (int ks = 0; ks < 4; ++ks) {
        a[ks]     = *reinterpret_cast<const bf16x8*>(agg + (size_t)r0c * 128 + ks * 32 + kg * 8);
        a[ks + 4] = *reinterpret_cast<const bf16x8*>(hbf + (size_t)r0c * 128 + ks * 32 + kg * 8);
    }

    f32x4 acc[3];
    #pragma unroll
    for (int nf = 0; nf < 3; ++nf) acc[nf] = (f32x4){0.f, 0.f, 0.f, 0.f};

    #pragma unroll
    for (int nf = 0; nf < 3; ++nf) {
        const ushort* bp = Wt2 + (size_t)(nf * 16 + l15) * 256 + kg * 64;
        bf16x8 b0 = *reinterpret_cast<const bf16x8*>(bp + 0);
        bf16x8 b1f = *reinterpret_cast<const bf16x8*>(bp + 8);
        bf16x8 b2f = *reinterpret_cast<const bf16x8*>(bp + 16);
        bf16x8 b3 = *reinterpret_cast<const bf16x8*>(bp + 24);
        bf16x8 b4 = *reinterpret_cast<const bf16x8*>(bp + 32);
        bf16x8 b5 = *reinterpret_cast<const bf16x8*>(bp + 40);
        bf16x8 b6 = *reinterpret_cast<const bf16x8*>(bp + 48);
        bf16x8 b7 = *reinterpret_cast<const bf16x8*>(bp + 56);
        acc[nf] = __builtin_amdgcn_mfma_f32_16x16x32_bf16(a[0], b0, acc[nf], 0, 0, 0);
        acc[nf] = __builtin_amdgcn_mfma_f32_16x16x32_bf16(a[1], b1f, acc[nf], 0, 0, 0);
        acc[nf] = __builtin_amdgcn_mfma_f32_16x16x32_bf16(a[2], b2f, acc[nf], 0, 0, 0);
        acc[nf] = __builtin_amdgcn_mfma_f32_16x16x32_bf16(a[3], b3, acc[nf], 0, 0, 0);
        acc[nf] = __builtin_amdgcn_mfma_f32_16x16x32_bf16(a[4], b4, acc[nf], 0, 0, 0);
        acc[nf] = __builtin_amdgcn_mfma_f32_16x16x32_bf16(a[5], b5, acc[nf], 0, 0, 0);
        acc[nf] = __builtin_amdgcn_mfma_f32_16x16x32_bf16(a[6], b6, acc[nf], 0, 0, 0);
        acc[nf] = __builtin_amdgcn_mfma_f32_16x16x32_bf16(a[7], b7, acc[nf], 0, 0, 0);
    }

    #pragma unroll
    for (int r = 0; r < 4; ++r) {
        int row = row_base + kg * 4 + r;
        float v[3];
        #pragma unroll
        for (int nf = 0; nf < 3; ++nf) {
            int col = nf * 16 + l15;
            v[nf] = (col < OUT_CH) ? (acc[nf][r] + b2[col]) : -3.0e38f;
        }
        float mx = fmaxf(fmaxf(v[0], v[1]), v[2]);
        #pragma unroll
        for (int s = 1; s < 16; s <<= 1) mx = fmaxf(mx, __shfl_xor(mx, s, 64));
        float se = 0.0f;
        #pragma unroll
        for (int nf = 0; nf < 3; ++nf) {
            int col = nf * 16 + l15;
            if (col < OUT_CH) se += expf(v[nf] - mx);
        }
        #pragma unroll
        for (int s = 1; s < 16; s <<= 1) se += __shfl_xor(se, s, 64);
        float lz = mx + logf(se);
        if (row < N_NODES) {
            #pragma unroll
            for (int nf = 0; nf < 3; ++nf) {
                int col = nf * 16 + l15;
                if (col < OUT_CH)
                    out[(size_t)row * OUT_CH + col] = v[nf] - lz;
            }
        }
    }
}

// ---------------- launch ----------------
extern "C" void kernel_launch(void* const* d_in, const int* in_sizes, int n_in,
                              void* d_out, int out_size, void* d_ws, size_t ws_size,
                              hipStream_t stream) {
    const float* x   = (const float*)d_in[0];
    const void*  ei  = d_in[1];
    const float* W1l = (const float*)d_in[2];
    const float* b1  = (const float*)d_in[3];
    const float* W1r = (const float*)d_in[4];
    const float* W2l = (const float*)d_in[5];
    const float* b2  = (const float*)d_in[6];
    const float* W2r = (const float*)d_in[7];
    float* out = (float*)d_out;

    // ws layout (~94.7 MB)
    char* ws = (char*)d_ws;
    int*      flag   = (int*)ws;
    int*      gcnt   = (int*)(ws + 4096);                       // NB*16 ints, 64B-strided
    int*      bbase  = (int*)(ws + 106496);                     // 196 ints
    ushort*   x_bf   = (ushort*)(ws + 131072);                  // 25.6 MB
    ushort*   h_bf   = (ushort*)(ws + 131072 + 25600000);       // 25.6 MB
    ushort*   agg_bf = (ushort*)(ws + 131072 + 51200000);       // 25.6 MB
    ushort*   Wt1    = (ushort*)(ws + 131072 + 76800000);       // 64 KB
    ushort*   Wt2    = (ushort*)(ws + 131072 + 76865536);       // 24 KB
    uint2*    gbuf   = (uint2*)(ws + 77021184);                 // 16.06 MB (196*10240*8)
    uint32_t* dmask  = (uint32_t*)(ws + 93077504);              // 1.6 MB (end ~94.7 MB)

    // d_out (16 MB) doubles as CSR scratch; fully consumed before layer2 writes.
    char* ob = (char*)d_out;
    int* csr    = (int*)ob;                        // 6.4 MB
    int* cursor = (int*)(ob + 6400000);            // 400 KB

    prep<<<2, 256, 0, stream>>>((const int*)ei, flag, gcnt);
    bucket_edges<<<(N_EDGES + TILE_EDGES - 1) / TILE_EDGES, 256, 0, stream>>>(
        ei, flag, gcnt, gbuf);
    bucket_scan<<<1, 256, 0, stream>>>(gcnt, bbase);
    build_csr<<<NB, 256, 0, stream>>>(gcnt, gbuf, bbase, csr, cursor);

    cvt_and_mask<<<2048, 256, 0, stream>>>(x, x_bf, dmask);
    cvt_w2<<<176, 256, 0, stream>>>(W1l, W1r, W2l, W2r, Wt1, Wt2);

    aggregate_mean_bf<<<(N_NODES + 3) / 4, 256, 0, stream>>>(x_bf, csr, cursor, agg_bf);
    layer1_mfma<<<2 * ((N_NODES + 63) / 64), 256, 0, stream>>>(agg_bf, x_bf, Wt1, b1, dmask, h_bf);
    aggregate_mean_bf<<<(N_NODES + 3) / 4, 256, 0, stream>>>(h_bf, csr, cursor, agg_bf);
    layer2_mfma<<<(N_NODES + 63) / 64, 256, 0, stream>>>(agg_bf, h_bf, Wt2, b2, out);
}

// Round 12
// 293.691 us; speedup vs baseline: 1.1426x; 1.1426x over previous
//
#include <hip/hip_runtime.h>
#include <stdint.h>
#include <stddef.h>

#define N_NODES 100000
#define N_EDGES 1600000
#define IN_CH 128
#define HID_CH 128
#define OUT_CH 40

#define NB 196            // buckets: b = dst >> 9 (512 nodes each)
#define GCAP 10240        // per-bucket capacity (mean 8163 + 22 sigma)
#define TILE_EDGES 2048   // edges per WG in bucket_edges
#define LCAP 40           // LDS slots per bucket per tile (mean 10.4 + 9 sigma; slow-path fallback)

#define N_MASK_WORDS 400000   // 100000*128/32
#define N_CVT4 3200000        // 100000*128/4

#define WROW 264          // LDS row stride (ushorts): 256 data + 8 pad -> uniform bank windows

typedef __attribute__((ext_vector_type(8))) short bf16x8;
typedef __attribute__((ext_vector_type(8))) unsigned short u16x8;
typedef __attribute__((ext_vector_type(4))) float f32x4;

// ---------------- bf16 helpers ----------------
__device__ __forceinline__ ushort f2bf(float f) {
    uint32_t u = __float_as_uint(f);
    uint32_t r = (u + 0x7FFFu + ((u >> 16) & 1u)) >> 16;   // RNE
    return (ushort)r;
}
__device__ __forceinline__ float bf2f(ushort u) {
    return __uint_as_float(((uint32_t)u) << 16);
}

// ---------------- threefry2x32 (JAX PRNG, key = (0,42)) ----------------
__device__ __forceinline__ uint32_t rotl32(uint32_t x, int r) {
    return (x << r) | (x >> (32 - r));
}

__device__ __forceinline__ void threefry2x32_k42(uint32_t x0, uint32_t x1,
                                                 uint32_t& o0, uint32_t& o1) {
    const uint32_t ks0 = 0u, ks1 = 42u;
    const uint32_t ks2 = 0u ^ 42u ^ 0x1BD11BDAu;
    x0 += ks0; x1 += ks1;
    x0 += x1; x1 = rotl32(x1, 13); x1 ^= x0;
    x0 += x1; x1 = rotl32(x1, 15); x1 ^= x0;
    x0 += x1; x1 = rotl32(x1, 26); x1 ^= x0;
    x0 += x1; x1 = rotl32(x1,  6); x1 ^= x0;
    x0 += ks1; x1 += ks2 + 1u;
    x0 += x1; x1 = rotl32(x1, 17); x1 ^= x0;
    x0 += x1; x1 = rotl32(x1, 29); x1 ^= x0;
    x0 += x1; x1 = rotl32(x1, 16); x1 ^= x0;
    x0 += x1; x1 = rotl32(x1, 24); x1 ^= x0;
    x0 += ks2; x1 += ks0 + 2u;
    x0 += x1; x1 = rotl32(x1, 13); x1 ^= x0;
    x0 += x1; x1 = rotl32(x1, 15); x1 ^= x0;
    x0 += x1; x1 = rotl32(x1, 26); x1 ^= x0;
    x0 += x1; x1 = rotl32(x1,  6); x1 ^= x0;
    x0 += ks0; x1 += ks1 + 3u;
    x0 += x1; x1 = rotl32(x1, 17); x1 ^= x0;
    x0 += x1; x1 = rotl32(x1, 29); x1 ^= x0;
    x0 += x1; x1 = rotl32(x1, 16); x1 ^= x0;
    x0 += x1; x1 = rotl32(x1, 24); x1 ^= x0;
    x0 += ks1; x1 += ks2 + 4u;
    x0 += x1; x1 = rotl32(x1, 13); x1 ^= x0;
    x0 += x1; x1 = rotl32(x1, 15); x1 ^= x0;
    x0 += x1; x1 = rotl32(x1, 26); x1 ^= x0;
    x0 += x1; x1 = rotl32(x1,  6); x1 ^= x0;
    x0 += ks2; x1 += ks0 + 5u;
    o0 = x0; o1 = x1;
}

// ---------------- edge load ----------------
__device__ __forceinline__ void load_edge(const void* ei, bool is32, int e,
                                          int& s, int& d) {
    if (is32) {
        const int* p = (const int*)ei;
        s = p[e]; d = p[N_EDGES + e];
    } else {
        const long long* p = (const long long*)ei;
        s = (int)p[e]; d = (int)p[N_EDGES + e];
    }
}

// ---------------- prep: sampled dtype detect (block 0) + zero gcnt (block 1) --------
__global__ __launch_bounds__(256) void prep(const int* __restrict__ ei32,
                                            int* __restrict__ flag,
                                            int* __restrict__ gcnt) {
    const int t = threadIdx.x;
    if (blockIdx.x == 0) {
        __shared__ int red[256];
        int local = 0;
        #pragma unroll
        for (int j = 0; j < 64; ++j) {
            int k = (t * 64 + j) * 97;           // max 1,589,151 < N_EDGES
            local |= ei32[2 * k + 1];
        }
        red[t] = local;
        __syncthreads();
        for (int off = 128; off; off >>= 1) {
            if (t < off) red[t] |= red[t + off];
            __syncthreads();
        }
        if (t == 0) *flag = (red[0] != 0);
    } else {
        for (int i = t; i < NB * 16; i += 256) gcnt[i] = 0;
    }
}

// ---------------- bucketed CSR build, pass 1: LDS-staged append ----------------
__global__ __launch_bounds__(256) void bucket_edges(
    const void* __restrict__ ei, const int* __restrict__ flag,
    int* __restrict__ gcnt, uint2* __restrict__ gbuf) {
    __shared__ uint2 lbuf[NB][LCAP];   // 62.7 KB
    __shared__ int lcnt[NB];
    const bool is32 = (*flag != 0);
    const int t = threadIdx.x;
    for (int b = t; b < NB; b += 256) lcnt[b] = 0;
    __syncthreads();
    const int base = blockIdx.x * TILE_EDGES;
    #pragma unroll
    for (int j = 0; j < TILE_EDGES / 256; ++j) {
        int e = base + j * 256 + t;
        if (e < N_EDGES) {
            int s, d;
            load_edge(ei, is32, e, s, d);
            int b = d >> 9;
            int pos = atomicAdd(&lcnt[b], 1);
            if (pos < LCAP) {
                lbuf[b][pos] = make_uint2((uint32_t)s, (uint32_t)d);
            } else {   // overflow slow path (statistically ~never; correctness-preserving)
                int gp = atomicAdd(&gcnt[b * 16], 1);
                gbuf[(size_t)b * GCAP + gp] = make_uint2((uint32_t)s, (uint32_t)d);
            }
        }
    }
    __syncthreads();
    if (t < NB) {
        int cnt = lcnt[t];
        if (cnt > LCAP) cnt = LCAP;
        if (cnt > 0) {
            int gp = atomicAdd(&gcnt[t * 16], cnt);
            uint2* dst = gbuf + (size_t)t * GCAP + gp;
            for (int i = 0; i < cnt; ++i) dst[i] = lbuf[t][i];
        }
    }
}

// exclusive scan of bucket totals (196 values, 1 block)
__global__ void bucket_scan(const int* __restrict__ gcnt, int* __restrict__ bbase) {
    __shared__ int s[256];
    int t = threadIdx.x;
    int tot = (t < NB) ? gcnt[t * 16] : 0;
    s[t] = tot;
    __syncthreads();
    for (int off = 1; off < 256; off <<= 1) {
        int a = (t >= off) ? s[t - off] : 0;
        __syncthreads();
        s[t] += a;
        __syncthreads();
    }
    if (t < NB) bbase[t] = s[t] - tot;   // exclusive
}

// pass 2: one WG per bucket -> exact degrees (histogram), scan, cursor, place.
__global__ __launch_bounds__(256) void build_csr(
    const int* __restrict__ gcnt, const uint2* __restrict__ gbuf,
    const int* __restrict__ bbase, int* __restrict__ csr, int* __restrict__ cursor) {
    __shared__ int hist[512];
    __shared__ int excl[512];
    __shared__ int cur[512];
    __shared__ int psum[256];
    const int b = blockIdx.x;
    const int t = threadIdx.x;
    hist[t] = 0; hist[t + 256] = 0;
    __syncthreads();
    const int base = bbase[b];
    const int cnt = gcnt[b * 16];
    const uint2* src = gbuf + (size_t)b * GCAP;
    for (int i = t; i < cnt; i += 256)
        atomicAdd(&hist[src[i].y & 511], 1);
    __syncthreads();
    int h0 = hist[2 * t], h1 = hist[2 * t + 1];
    psum[t] = h0 + h1;
    __syncthreads();
    int v = psum[t];
    for (int off = 1; off < 256; off <<= 1) {
        int a = (t >= off) ? psum[t - off] : 0;
        __syncthreads();
        psum[t] += a;
        __syncthreads();
    }
    int pex = psum[t] - v;
    excl[2 * t] = pex;
    excl[2 * t + 1] = pex + h0;
    cur[2 * t] = pex;
    cur[2 * t + 1] = pex + h0;
    __syncthreads();
    for (int j = t; j < 512; j += 256) {
        int node = b * 512 + j;
        if (node < N_NODES) cursor[node] = base + excl[j] + hist[j];
    }
    for (int i = t; i < cnt; i += 256) {
        uint2 p = src[i];
        int pos = atomicAdd(&cur[p.y & 511], 1);
        csr[base + pos] = (int)p.x;
    }
}

// ---------------- fused: x -> bf16 conversion + dropout mask precompute ----------------
__global__ __launch_bounds__(256) void cvt_and_mask(
    const float* __restrict__ in, ushort* __restrict__ out,
    uint32_t* __restrict__ mask) {
    const long gid = (long)blockIdx.x * blockDim.x + threadIdx.x;
    const long stride = (long)gridDim.x * blockDim.x;
    for (long i = gid; i < N_CVT4; i += stride) {
        float4 v = *reinterpret_cast<const float4*>(in + i * 4);
        ushort4 r;
        r.x = f2bf(v.x); r.y = f2bf(v.y); r.z = f2bf(v.z); r.w = f2bf(v.w);
        *reinterpret_cast<ushort4*>(out + i * 4) = r;
    }
    for (long w = gid; w < N_MASK_WORDS; w += stride) {
        uint32_t m = 0;
        #pragma unroll 4
        for (int j = 0; j < 32; ++j) {
            uint32_t o0, o1;
            threefry2x32_k42(0u, (uint32_t)w * 32u + j, o0, o1);
            m |= ((o0 ^ o1) >> 31) << j;
        }
        mask[w] = m;
    }
}

// Plain transposed layout: Wt[n*256 + k] = bf16( k<128 ? Wl[k][n] : Wr[k-128][n] )
__global__ void cvt_w2(const float* __restrict__ W1l, const float* __restrict__ W1r,
                       const float* __restrict__ W2l, const float* __restrict__ W2r,
                       ushort* __restrict__ Wt1, ushort* __restrict__ Wt2) {
    int blk = blockIdx.x;
    int k = threadIdx.x;
    if (blk < 128) {
        int n = blk;
        float v = (k < 128) ? W1l[(size_t)k * 128 + n] : W1r[(size_t)(k - 128) * 128 + n];
        Wt1[(size_t)n * 256 + k] = f2bf(v);
    } else {
        int n = blk - 128;
        float v = 0.0f;
        if (n < OUT_CH)
            v = (k < 128) ? W2l[(size_t)k * 40 + n] : W2r[(size_t)(k - 128) * 40 + n];
        Wt2[(size_t)n * 256 + k] = f2bf(v);
    }
}

// ---------------- gather-based mean aggregation (bf16, 16B/lane) ----------------
__global__ __launch_bounds__(256) void aggregate_mean_bf(
    const ushort* __restrict__ feat, const int* __restrict__ csr,
    const int* __restrict__ cursor, ushort* __restrict__ out) {
    int node = blockIdx.x * 4 + (threadIdx.x >> 6);
    if (node >= N_NODES) return;
    const int lane = threadIdx.x & 63;
    const int g = lane >> 4;        // 0..3 edge subgroup
    const int c = lane & 15;        // col group: channels c*8..c*8+7
    const int beg = (node > 0) ? cursor[node - 1] : 0;
    const int end = cursor[node];

    float acc[8];
    #pragma unroll
    for (int j = 0; j < 8; ++j) acc[j] = 0.0f;

    int e = beg + g;
    for (; e + 4 < end; e += 8) {
        int s0 = csr[e];
        int s1 = csr[e + 4];
        bf16x8 v0 = *reinterpret_cast<const bf16x8*>(feat + (size_t)s0 * 128 + c * 8);
        bf16x8 v1 = *reinterpret_cast<const bf16x8*>(feat + (size_t)s1 * 128 + c * 8);
        #pragma unroll
        for (int j = 0; j < 8; ++j) acc[j] += bf2f((ushort)v0[j]);
        #pragma unroll
        for (int j = 0; j < 8; ++j) acc[j] += bf2f((ushort)v1[j]);
    }
    if (e < end) {
        int s0 = csr[e];
        bf16x8 v0 = *reinterpret_cast<const bf16x8*>(feat + (size_t)s0 * 128 + c * 8);
        #pragma unroll
        for (int j = 0; j < 8; ++j) acc[j] += bf2f((ushort)v0[j]);
    }

    // sum the 4 edge subgroups (lanes with equal c)
    #pragma unroll
    for (int j = 0; j < 8; ++j) {
        acc[j] += __shfl_xor(acc[j], 16, 64);
        acc[j] += __shfl_xor(acc[j], 32, 64);
    }

    if (g == 0) {
        int deg = end - beg;
        float inv = (deg > 0) ? (1.0f / (float)deg) : 0.0f;
        u16x8 r;
        #pragma unroll
        for (int j = 0; j < 8; ++j) r[j] = f2bf(acc[j] * inv);
        *reinterpret_cast<u16x8*>(out + (size_t)node * 128 + c * 8) = r;
    }
}

// ---------------- layer 1 MFMA (LDS-staged weights) ----------------
// Block: 64 rows x 64 cols (col half by blockIdx&1), 4 waves x 16 rows.
// Weights staged once into LDS (32KB + pad); B-frags via ds_read_b128 with
// short, compiler-scheduled lgkmcnt waits instead of L2-latency chains.
__global__ __launch_bounds__(256) void layer1_mfma(
    const ushort* __restrict__ agg, const ushort* __restrict__ xbf,
    const ushort* __restrict__ Wt, const float* __restrict__ b1,
    const uint32_t* __restrict__ dmask, ushort* __restrict__ h) {
    __shared__ ushort wlds[64 * WROW];   // 33.8 KB
    const int tid = threadIdx.x;
    const int lane = tid & 63;
    const int l15 = lane & 15, kg = lane >> 4;
    const int colBase = (blockIdx.x & 1) * 64;
    const int row_base = ((blockIdx.x >> 1) * 4 + (tid >> 6)) * 16;

    // stage 64 cols x 256 k (linear copy, 16B chunks)
    #pragma unroll
    for (int i = 0; i < 8; ++i) {
        int idx = tid + i * 256;
        int r = idx >> 5, c = idx & 31;
        u16x8 v = *reinterpret_cast<const u16x8*>(Wt + (size_t)(colBase + r) * 256 + c * 8);
        *reinterpret_cast<u16x8*>(wlds + r * WROW + c * 8) = v;
    }
    __syncthreads();
    if (row_base >= N_NODES) return;   // after barrier; no further barriers

    int r0 = row_base + l15;
    int r0c = (r0 < N_NODES) ? r0 : (N_NODES - 1);

    bf16x8 a[8];
    #pragma unroll
    for (int ks = 0; ks < 4; ++ks) {
        a[ks]     = *reinterpret_cast<const bf16x8*>(agg + (size_t)r0c * 128 + ks * 32 + kg * 8);
        a[ks + 4] = *reinterpret_cast<const bf16x8*>(xbf + (size_t)r0c * 128 + ks * 32 + kg * 8);
    }

    f32x4 acc[4];
    #pragma unroll
    for (int nf = 0; nf < 4; ++nf) acc[nf] = (f32x4){0.f, 0.f, 0.f, 0.f};

    #pragma unroll
    for (int nf = 0; nf < 4; ++nf) {
        const ushort* bp = wlds + (nf * 16 + l15) * WROW + kg * 8;
        #pragma unroll
        for (int ks = 0; ks < 8; ++ks) {
            bf16x8 b = *reinterpret_cast<const bf16x8*>(bp + ks * 32);
            acc[nf] = __builtin_amdgcn_mfma_f32_16x16x32_bf16(a[ks], b, acc[nf], 0, 0, 0);
        }
    }

    #pragma unroll
    for (int r = 0; r < 4; ++r) {
        int row = row_base + kg * 4 + r;
        if (row < N_NODES) {
            uint4 mw = *reinterpret_cast<const uint4*>(dmask + (size_t)row * 4);
            const uint32_t* mwp = reinterpret_cast<const uint32_t*>(&mw);
            #pragma unroll
            for (int nf = 0; nf < 4; ++nf) {
                int col = colBase + nf * 16 + l15;
                float v = acc[nf][r] + b1[col];
                v = fmaxf(v, 0.0f) * 2.0f;
                if ((mwp[col >> 5] >> (col & 31)) & 1u) v = 0.0f;
                h[(size_t)row * 128 + col] = f2bf(v);
            }
        }
    }
}

// ---------------- layer 2 MFMA (LDS-staged weights) ----------------
__global__ __launch_bounds__(256) void layer2_mfma(
    const ushort* __restrict__ agg, const ushort* __restrict__ hbf,
    const ushort* __restrict__ Wt2, const float* __restrict__ b2,
    float* __restrict__ out) {
    __shared__ ushort wlds[48 * WROW];   // 25.3 KB
    const int tid = threadIdx.x;
    const int lane = tid & 63;
    const int l15 = lane & 15, kg = lane >> 4;
    const int row_base = (blockIdx.x * 4 + (tid >> 6)) * 16;

    // stage 48 cols x 256 k
    #pragma unroll
    for (int i = 0; i < 6; ++i) {
        int idx = tid + i * 256;
        int r = idx >> 5, c = idx & 31;
        u16x8 v = *reinterpret_cast<const u16x8*>(Wt2 + (size_t)r * 256 + c * 8);
        *reinterpret_cast<u16x8*>(wlds + r * WROW + c * 8) = v;
    }
    __syncthreads();
    if (row_base >= N_NODES) return;

    int r0 = row_base + l15;
    int r0c = (r0 < N_NODES) ? r0 : (N_NODES - 1);

    bf16x8 a[8];
    #pragma unroll
    for (int ks = 0; ks < 4; ++ks) {
        a[ks]     = *reinterpret_cast<const bf16x8*>(agg + (size_t)r0c * 128 + ks * 32 + kg * 8);
        a[ks + 4] = *reinterpret_cast<const bf16x8*>(hbf + (size_t)r0c * 128 + ks * 32 + kg * 8);
    }

    f32x4 acc[3];
    #pragma unroll
    for (int nf = 0; nf < 3; ++nf) acc[nf] = (f32x4){0.f, 0.f, 0.f, 0.f};

    #pragma unroll
    for (int nf = 0; nf < 3; ++nf) {
        const ushort* bp = wlds + (nf * 16 + l15) * WROW + kg * 8;
        #pragma unroll
        for (int ks = 0; ks < 8; ++ks) {
            bf16x8 b = *reinterpret_cast<const bf16x8*>(bp + ks * 32);
            acc[nf] = __builtin_amdgcn_mfma_f32_16x16x32_bf16(a[ks], b, acc[nf], 0, 0, 0);
        }
    }

    #pragma unroll
    for (int r = 0; r < 4; ++r) {
        int row = row_base + kg * 4 + r;
        float v[3];
        #pragma unroll
        for (int nf = 0; nf < 3; ++nf) {
            int col = nf * 16 + l15;
            v[nf] = (col < OUT_CH) ? (acc[nf][r] + b2[col]) : -3.0e38f;
        }
        float mx = fmaxf(fmaxf(v[0], v[1]), v[2]);
        #pragma unroll
        for (int s = 1; s < 16; s <<= 1) mx = fmaxf(mx, __shfl_xor(mx, s, 64));
        float se = 0.0f;
        #pragma unroll
        for (int nf = 0; nf < 3; ++nf) {
            int col = nf * 16 + l15;
            if (col < OUT_CH) se += expf(v[nf] - mx);
        }
        #pragma unroll
        for (int s = 1; s < 16; s <<= 1) se += __shfl_xor(se, s, 64);
        float lz = mx + logf(se);
        if (row < N_NODES) {
            #pragma unroll
            for (int nf = 0; nf < 3; ++nf) {
                int col = nf * 16 + l15;
                if (col < OUT_CH)
                    out[(size_t)row * OUT_CH + col] = v[nf] - lz;
            }
        }
    }
}

// ---------------- launch ----------------
extern "C" void kernel_launch(void* const* d_in, const int* in_sizes, int n_in,
                              void* d_out, int out_size, void* d_ws, size_t ws_size,
                              hipStream_t stream) {
    const float* x   = (const float*)d_in[0];
    const void*  ei  = d_in[1];
    const float* W1l = (const float*)d_in[2];
    const float* b1  = (const float*)d_in[3];
    const float* W1r = (const float*)d_in[4];
    const float* W2l = (const float*)d_in[5];
    const float* b2  = (const float*)d_in[6];
    const float* W2r = (const float*)d_in[7];
    float* out = (float*)d_out;

    // ws layout (~94.7 MB)
    char* ws = (char*)d_ws;
    int*      flag   = (int*)ws;
    int*      gcnt   = (int*)(ws + 4096);                       // NB*16 ints, 64B-strided
    int*      bbase  = (int*)(ws + 106496);                     // 196 ints
    ushort*   x_bf   = (ushort*)(ws + 131072);                  // 25.6 MB
    ushort*   h_bf   = (ushort*)(ws + 131072 + 25600000);       // 25.6 MB
    ushort*   agg_bf = (ushort*)(ws + 131072 + 51200000);       // 25.6 MB
    ushort*   Wt1    = (ushort*)(ws + 131072 + 76800000);       // 64 KB
    ushort*   Wt2    = (ushort*)(ws + 131072 + 76865536);       // 24 KB
    uint2*    gbuf   = (uint2*)(ws + 77021184);                 // 16.06 MB (196*10240*8)
    uint32_t* dmask  = (uint32_t*)(ws + 93077504);              // 1.6 MB (end ~94.7 MB)

    // d_out (16 MB) doubles as CSR scratch; fully consumed before layer2 writes.
    char* ob = (char*)d_out;
    int* csr    = (int*)ob;                        // 6.4 MB
    int* cursor = (int*)(ob + 6400000);            // 400 KB

    prep<<<2, 256, 0, stream>>>((const int*)ei, flag, gcnt);
    bucket_edges<<<(N_EDGES + TILE_EDGES - 1) / TILE_EDGES, 256, 0, stream>>>(
        ei, flag, gcnt, gbuf);
    bucket_scan<<<1, 256, 0, stream>>>(gcnt, bbase);
    build_csr<<<NB, 256, 0, stream>>>(gcnt, gbuf, bbase, csr, cursor);

    cvt_and_mask<<<2048, 256, 0, stream>>>(x, x_bf, dmask);
    cvt_w2<<<176, 256, 0, stream>>>(W1l, W1r, W2l, W2r, Wt1, Wt2);

    aggregate_mean_bf<<<(N_NODES + 3) / 4, 256, 0, stream>>>(x_bf, csr, cursor, agg_bf);
    layer1_mfma<<<2 * ((N_NODES + 63) / 64), 256, 0, stream>>>(agg_bf, x_bf, Wt1, b1, dmask, h_bf);
    aggregate_mean_bf<<<(N_NODES + 3) / 4, 256, 0, stream>>>(h_bf, csr, cursor, agg_bf);
    layer2_mfma<<<(N_NODES + 63) / 64, 256, 0, stream>>>(agg_bf, h_bf, Wt2, b2, out);
}

// Round 14
// 293.008 us; speedup vs baseline: 1.1453x; 1.0023x over previous
//
#include <hip/hip_runtime.h>
#include <stdint.h>
#include <stddef.h>

#define N_NODES 100000
#define N_EDGES 1600000
#define IN_CH 128
#define HID_CH 128
#define OUT_CH 40

#define NB 196            // buckets: b = dst >> 9 (512 nodes each)
#define GCAP 10240        // per-bucket capacity (mean 8163 + 22 sigma)
#define TILE_EDGES 2048   // edges per WG in bucket_edges
#define LCAP 40           // LDS slots per bucket per tile (mean 10.4 + 9 sigma; slow-path fallback)

#define N_MASK_WORDS 400000   // 100000*128/32
#define N_CVT4 3200000        // 100000*128/4

#define WROW 264          // LDS row stride (ushorts): 256 data + 8 pad

typedef __attribute__((ext_vector_type(8))) short bf16x8;
typedef __attribute__((ext_vector_type(8))) unsigned short u16x8;
typedef __attribute__((ext_vector_type(4))) float f32x4;

// ---------------- bf16 helpers ----------------
__device__ __forceinline__ ushort f2bf(float f) {
    uint32_t u = __float_as_uint(f);
    uint32_t r = (u + 0x7FFFu + ((u >> 16) & 1u)) >> 16;   // RNE
    return (ushort)r;
}
__device__ __forceinline__ float bf2f(ushort u) {
    return __uint_as_float(((uint32_t)u) << 16);
}

// ---------------- threefry2x32 (JAX PRNG, key = (0,42)) ----------------
__device__ __forceinline__ uint32_t rotl32(uint32_t x, int r) {
    return (x << r) | (x >> (32 - r));
}

__device__ __forceinline__ void threefry2x32_k42(uint32_t x0, uint32_t x1,
                                                 uint32_t& o0, uint32_t& o1) {
    const uint32_t ks0 = 0u, ks1 = 42u;
    const uint32_t ks2 = 0u ^ 42u ^ 0x1BD11BDAu;
    x0 += ks0; x1 += ks1;
    x0 += x1; x1 = rotl32(x1, 13); x1 ^= x0;
    x0 += x1; x1 = rotl32(x1, 15); x1 ^= x0;
    x0 += x1; x1 = rotl32(x1, 26); x1 ^= x0;
    x0 += x1; x1 = rotl32(x1,  6); x1 ^= x0;
    x0 += ks1; x1 += ks2 + 1u;
    x0 += x1; x1 = rotl32(x1, 17); x1 ^= x0;
    x0 += x1; x1 = rotl32(x1, 29); x1 ^= x0;
    x0 += x1; x1 = rotl32(x1, 16); x1 ^= x0;
    x0 += x1; x1 = rotl32(x1, 24); x1 ^= x0;
    x0 += ks2; x1 += ks0 + 2u;
    x0 += x1; x1 = rotl32(x1, 13); x1 ^= x0;
    x0 += x1; x1 = rotl32(x1, 15); x1 ^= x0;
    x0 += x1; x1 = rotl32(x1, 26); x1 ^= x0;
    x0 += x1; x1 = rotl32(x1,  6); x1 ^= x0;
    x0 += ks0; x1 += ks1 + 3u;
    x0 += x1; x1 = rotl32(x1, 17); x1 ^= x0;
    x0 += x1; x1 = rotl32(x1, 29); x1 ^= x0;
    x0 += x1; x1 = rotl32(x1, 16); x1 ^= x0;
    x0 += x1; x1 = rotl32(x1, 24); x1 ^= x0;
    x0 += ks1; x1 += ks2 + 4u;
    x0 += x1; x1 = rotl32(x1, 13); x1 ^= x0;
    x0 += x1; x1 = rotl32(x1, 15); x1 ^= x0;
    x0 += x1; x1 = rotl32(x1, 26); x1 ^= x0;
    x0 += x1; x1 = rotl32(x1,  6); x1 ^= x0;
    x0 += ks2; x1 += ks0 + 5u;
    o0 = x0; o1 = x1;
}

// ---------------- edge load ----------------
__device__ __forceinline__ void load_edge(const void* ei, bool is32, int e,
                                          int& s, int& d) {
    if (is32) {
        const int* p = (const int*)ei;
        s = p[e]; d = p[N_EDGES + e];
    } else {
        const long long* p = (const long long*)ei;
        s = (int)p[e]; d = (int)p[N_EDGES + e];
    }
}

// ---------------- prep: sampled dtype detect (block 0) + zero gcnt (block 1) --------
__global__ __launch_bounds__(256) void prep(const int* __restrict__ ei32,
                                            int* __restrict__ flag,
                                            int* __restrict__ gcnt) {
    const int t = threadIdx.x;
    if (blockIdx.x == 0) {
        __shared__ int red[256];
        int local = 0;
        #pragma unroll
        for (int j = 0; j < 64; ++j) {
            int k = (t * 64 + j) * 97;           // max 1,589,151 < N_EDGES
            local |= ei32[2 * k + 1];
        }
        red[t] = local;
        __syncthreads();
        for (int off = 128; off; off >>= 1) {
            if (t < off) red[t] |= red[t + off];
            __syncthreads();
        }
        if (t == 0) *flag = (red[0] != 0);
    } else {
        for (int i = t; i < NB * 16; i += 256) gcnt[i] = 0;
    }
}

// ---------------- bucketed CSR build, pass 1: LDS-staged append ----------------
__global__ __launch_bounds__(256) void bucket_edges(
    const void* __restrict__ ei, const int* __restrict__ flag,
    int* __restrict__ gcnt, uint2* __restrict__ gbuf) {
    __shared__ uint2 lbuf[NB][LCAP];   // 62.7 KB
    __shared__ int lcnt[NB];
    const bool is32 = (*flag != 0);
    const int t = threadIdx.x;
    for (int b = t; b < NB; b += 256) lcnt[b] = 0;
    __syncthreads();
    const int base = blockIdx.x * TILE_EDGES;
    #pragma unroll
    for (int j = 0; j < TILE_EDGES / 256; ++j) {
        int e = base + j * 256 + t;
        if (e < N_EDGES) {
            int s, d;
            load_edge(ei, is32, e, s, d);
            int b = d >> 9;
            int pos = atomicAdd(&lcnt[b], 1);
            if (pos < LCAP) {
                lbuf[b][pos] = make_uint2((uint32_t)s, (uint32_t)d);
            } else {   // overflow slow path (statistically ~never; correctness-preserving)
                int gp = atomicAdd(&gcnt[b * 16], 1);
                gbuf[(size_t)b * GCAP + gp] = make_uint2((uint32_t)s, (uint32_t)d);
            }
        }
    }
    __syncthreads();
    if (t < NB) {
        int cnt = lcnt[t];
        if (cnt > LCAP) cnt = LCAP;
        if (cnt > 0) {
            int gp = atomicAdd(&gcnt[t * 16], cnt);
            uint2* dst = gbuf + (size_t)t * GCAP + gp;
            for (int i = 0; i < cnt; ++i) dst[i] = lbuf[t][i];
        }
    }
}

// exclusive scan of bucket totals (196 values, 1 block)
__global__ void bucket_scan(const int* __restrict__ gcnt, int* __restrict__ bbase) {
    __shared__ int s[256];
    int t = threadIdx.x;
    int tot = (t < NB) ? gcnt[t * 16] : 0;
    s[t] = tot;
    __syncthreads();
    for (int off = 1; off < 256; off <<= 1) {
        int a = (t >= off) ? s[t - off] : 0;
        __syncthreads();
        s[t] += a;
        __syncthreads();
    }
    if (t < NB) bbase[t] = s[t] - tot;   // exclusive
}

// pass 2: one WG per bucket -> exact degrees (histogram), scan, cursor, place.
__global__ __launch_bounds__(256) void build_csr(
    const int* __restrict__ gcnt, const uint2* __restrict__ gbuf,
    const int* __restrict__ bbase, int* __restrict__ csr, int* __restrict__ cursor) {
    __shared__ int hist[512];
    __shared__ int excl[512];
    __shared__ int cur[512];
    __shared__ int psum[256];
    const int b = blockIdx.x;
    const int t = threadIdx.x;
    hist[t] = 0; hist[t + 256] = 0;
    __syncthreads();
    const int base = bbase[b];
    const int cnt = gcnt[b * 16];
    const uint2* src = gbuf + (size_t)b * GCAP;
    for (int i = t; i < cnt; i += 256)
        atomicAdd(&hist[src[i].y & 511], 1);
    __syncthreads();
    int h0 = hist[2 * t], h1 = hist[2 * t + 1];
    psum[t] = h0 + h1;
    __syncthreads();
    int v = psum[t];
    for (int off = 1; off < 256; off <<= 1) {
        int a = (t >= off) ? psum[t - off] : 0;
        __syncthreads();
        psum[t] += a;
        __syncthreads();
    }
    int pex = psum[t] - v;
    excl[2 * t] = pex;
    excl[2 * t + 1] = pex + h0;
    cur[2 * t] = pex;
    cur[2 * t + 1] = pex + h0;
    __syncthreads();
    for (int j = t; j < 512; j += 256) {
        int node = b * 512 + j;
        if (node < N_NODES) cursor[node] = base + excl[j] + hist[j];
    }
    for (int i = t; i < cnt; i += 256) {
        uint2 p = src[i];
        int pos = atomicAdd(&cur[p.y & 511], 1);
        csr[base + pos] = (int)p.x;
    }
}

// ---------------- fused: x -> bf16 conversion + dropout mask precompute ----------------
__global__ __launch_bounds__(256) void cvt_and_mask(
    const float* __restrict__ in, ushort* __restrict__ out,
    uint32_t* __restrict__ mask) {
    const long gid = (long)blockIdx.x * blockDim.x + threadIdx.x;
    const long stride = (long)gridDim.x * blockDim.x;
    for (long i = gid; i < N_CVT4; i += stride) {
        float4 v = *reinterpret_cast<const float4*>(in + i * 4);
        ushort4 r;
        r.x = f2bf(v.x); r.y = f2bf(v.y); r.z = f2bf(v.z); r.w = f2bf(v.w);
        *reinterpret_cast<ushort4*>(out + i * 4) = r;
    }
    for (long w = gid; w < N_MASK_WORDS; w += stride) {
        uint32_t m = 0;
        #pragma unroll 4
        for (int j = 0; j < 32; ++j) {
            uint32_t o0, o1;
            threefry2x32_k42(0u, (uint32_t)w * 32u + j, o0, o1);
            m |= ((o0 ^ o1) >> 31) << j;
        }
        mask[w] = m;
    }
}

// Plain transposed layout: Wt[n*256 + k] = bf16( k<128 ? Wl[k][n] : Wr[k-128][n] )
__global__ void cvt_w2(const float* __restrict__ W1l, const float* __restrict__ W1r,
                       const float* __restrict__ W2l, const float* __restrict__ W2r,
                       ushort* __restrict__ Wt1, ushort* __restrict__ Wt2) {
    int blk = blockIdx.x;
    int k = threadIdx.x;
    if (blk < 128) {
        int n = blk;
        float v = (k < 128) ? W1l[(size_t)k * 128 + n] : W1r[(size_t)(k - 128) * 128 + n];
        Wt1[(size_t)n * 256 + k] = f2bf(v);
    } else {
        int n = blk - 128;
        float v = 0.0f;
        if (n < OUT_CH)
            v = (k < 128) ? W2l[(size_t)k * 40 + n] : W2r[(size_t)(k - 128) * 40 + n];
        Wt2[(size_t)n * 256 + k] = f2bf(v);
    }
}

// ---------------- gather-based mean aggregation (uniform csr-prefetch + shfl) --------
// One wave per node.  Lane l prefetches csr[beg+l] (one coalesced load covers
// deg<=64).  The edge loop is WAVE-UNIFORM (k = 0..ceil(nfull/4)-1, same for
// all lanes): the __shfl source lane is always active (fixes the R13 bug where
// divergent subgroup exit made bpermute read an EXEC=0 lane).  Out-of-range
// edges are handled by weighting the accumulate with w in {0,1} (exact) and
// clamping the shfl source to a valid edge.
__global__ __launch_bounds__(256) void aggregate_mean_bf(
    const ushort* __restrict__ feat, const int* __restrict__ csr,
    const int* __restrict__ cursor, ushort* __restrict__ out) {
    int node = blockIdx.x * 4 + (threadIdx.x >> 6);
    if (node >= N_NODES) return;
    const int lane = threadIdx.x & 63;
    const int g = lane >> 4;        // 0..3 edge subgroup
    const int c = lane & 15;        // col group: channels c*8..c*8+7
    const int beg = (node > 0) ? cursor[node - 1] : 0;
    const int end = cursor[node];
    const int deg = end - beg;

    // one coalesced 64-wide index prefetch
    int myidx = (lane < deg) ? csr[beg + lane] : 0;

    float acc[8];
    #pragma unroll
    for (int j = 0; j < 8; ++j) acc[j] = 0.0f;

    const int nfull = (deg < 64) ? deg : 64;
    const int niter = (nfull + 3) >> 2;   // wave-uniform trip count
    #pragma unroll 4
    for (int k = 0; k < niter; ++k) {
        int e = g + 4 * k;
        bool valid = (e < nfull);
        int es = valid ? e : 0;            // clamped source: always < deg
        int s = __shfl(myidx, es, 64);     // uniform exec -> source always active
        float w = valid ? 1.0f : 0.0f;
        bf16x8 v = *reinterpret_cast<const bf16x8*>(feat + (size_t)s * 128 + c * 8);
        #pragma unroll
        for (int j = 0; j < 8; ++j) acc[j] += w * bf2f((ushort)v[j]);
    }
    // rare tail (deg > 64), direct loads
    for (int e = 64 + g; e < deg; e += 4) {
        int s = csr[beg + e];
        bf16x8 v = *reinterpret_cast<const bf16x8*>(feat + (size_t)s * 128 + c * 8);
        #pragma unroll
        for (int j = 0; j < 8; ++j) acc[j] += bf2f((ushort)v[j]);
    }

    // sum the 4 edge subgroups (lanes with equal c)
    #pragma unroll
    for (int j = 0; j < 8; ++j) {
        acc[j] += __shfl_xor(acc[j], 16, 64);
        acc[j] += __shfl_xor(acc[j], 32, 64);
    }

    if (g == 0) {
        float inv = (deg > 0) ? (1.0f / (float)deg) : 0.0f;
        u16x8 r;
        #pragma unroll
        for (int j = 0; j < 8; ++j) r[j] = f2bf(acc[j] * inv);
        *reinterpret_cast<u16x8*>(out + (size_t)node * 128 + c * 8) = r;
    }
}

// ---------------- layer 1 MFMA (LDS-staged weights) ----------------
__global__ __launch_bounds__(256) void layer1_mfma(
    const ushort* __restrict__ agg, const ushort* __restrict__ xbf,
    const ushort* __restrict__ Wt, const float* __restrict__ b1,
    const uint32_t* __restrict__ dmask, ushort* __restrict__ h) {
    __shared__ ushort wlds[64 * WROW];   // 33.8 KB
    const int tid = threadIdx.x;
    const int lane = tid & 63;
    const int l15 = lane & 15, kg = lane >> 4;
    const int colBase = (blockIdx.x & 1) * 64;
    const int row_base = ((blockIdx.x >> 1) * 4 + (tid >> 6)) * 16;

    // stage 64 cols x 256 k (linear copy, 16B chunks)
    #pragma unroll
    for (int i = 0; i < 8; ++i) {
        int idx = tid + i * 256;
        int r = idx >> 5, c = idx & 31;
        u16x8 v = *reinterpret_cast<const u16x8*>(Wt + (size_t)(colBase + r) * 256 + c * 8);
        *reinterpret_cast<u16x8*>(wlds + r * WROW + c * 8) = v;
    }
    __syncthreads();
    if (row_base >= N_NODES) return;   // after barrier; no further barriers

    int r0 = row_base + l15;
    int r0c = (r0 < N_NODES) ? r0 : (N_NODES - 1);

    bf16x8 a[8];
    #pragma unroll
    for (int ks = 0; ks < 4; ++ks) {
        a[ks]     = *reinterpret_cast<const bf16x8*>(agg + (size_t)r0c * 128 + ks * 32 + kg * 8);
        a[ks + 4] = *reinterpret_cast<const bf16x8*>(xbf + (size_t)r0c * 128 + ks * 32 + kg * 8);
    }

    f32x4 acc[4];
    #pragma unroll
    for (int nf = 0; nf < 4; ++nf) acc[nf] = (f32x4){0.f, 0.f, 0.f, 0.f};

    #pragma unroll
    for (int nf = 0; nf < 4; ++nf) {
        const ushort* bp = wlds + (nf * 16 + l15) * WROW + kg * 8;
        #pragma unroll
        for (int ks = 0; ks < 8; ++ks) {
            bf16x8 b = *reinterpret_cast<const bf16x8*>(bp + ks * 32);
            acc[nf] = __builtin_amdgcn_mfma_f32_16x16x32_bf16(a[ks], b, acc[nf], 0, 0, 0);
        }
    }

    #pragma unroll
    for (int r = 0; r < 4; ++r) {
        int row = row_base + kg * 4 + r;
        if (row < N_NODES) {
            uint4 mw = *reinterpret_cast<const uint4*>(dmask + (size_t)row * 4);
            const uint32_t* mwp = reinterpret_cast<const uint32_t*>(&mw);
            #pragma unroll
            for (int nf = 0; nf < 4; ++nf) {
                int col = colBase + nf * 16 + l15;
                float v = acc[nf][r] + b1[col];
                v = fmaxf(v, 0.0f) * 2.0f;
                if ((mwp[col >> 5] >> (col & 31)) & 1u) v = 0.0f;
                h[(size_t)row * 128 + col] = f2bf(v);
            }
        }
    }
}

// ---------------- layer 2 MFMA (LDS-staged weights) ----------------
__global__ __launch_bounds__(256) void layer2_mfma(
    const ushort* __restrict__ agg, const ushort* __restrict__ hbf,
    const ushort* __restrict__ Wt2, const float* __restrict__ b2,
    float* __restrict__ out) {
    __shared__ ushort wlds[48 * WROW];   // 25.3 KB
    const int tid = threadIdx.x;
    const int lane = tid & 63;
    const int l15 = lane & 15, kg = lane >> 4;
    const int row_base = (blockIdx.x * 4 + (tid >> 6)) * 16;

    // stage 48 cols x 256 k
    #pragma unroll
    for (int i = 0; i < 6; ++i) {
        int idx = tid + i * 256;
        int r = idx >> 5, c = idx & 31;
        u16x8 v = *reinterpret_cast<const u16x8*>(Wt2 + (size_t)r * 256 + c * 8);
        *reinterpret_cast<u16x8*>(wlds + r * WROW + c * 8) = v;
    }
    __syncthreads();
    if (row_base >= N_NODES) return;

    int r0 = row_base + l15;
    int r0c = (r0 < N_NODES) ? r0 : (N_NODES - 1);

    bf16x8 a[8];
    #pragma unroll
    for (int ks = 0; ks < 4; ++ks) {
        a[ks]     = *reinterpret_cast<const bf16x8*>(agg + (size_t)r0c * 128 + ks * 32 + kg * 8);
        a[ks + 4] = *reinterpret_cast<const bf16x8*>(hbf + (size_t)r0c * 128 + ks * 32 + kg * 8);
    }

    f32x4 acc[3];
    #pragma unroll
    for (int nf = 0; nf < 3; ++nf) acc[nf] = (f32x4){0.f, 0.f, 0.f, 0.f};

    #pragma unroll
    for (int nf = 0; nf < 3; ++nf) {
        const ushort* bp = wlds + (nf * 16 + l15) * WROW + kg * 8;
        #pragma unroll
        for (int ks = 0; ks < 8; ++ks) {
            bf16x8 b = *reinterpret_cast<const bf16x8*>(bp + ks * 32);
            acc[nf] = __builtin_amdgcn_mfma_f32_16x16x32_bf16(a[ks], b, acc[nf], 0, 0, 0);
        }
    }

    #pragma unroll
    for (int r = 0; r < 4; ++r) {
        int row = row_base + kg * 4 + r;
        float v[3];
        #pragma unroll
        for (int nf = 0; nf < 3; ++nf) {
            int col = nf * 16 + l15;
            v[nf] = (col < OUT_CH) ? (acc[nf][r] + b2[col]) : -3.0e38f;
        }
        float mx = fmaxf(fmaxf(v[0], v[1]), v[2]);
        #pragma unroll
        for (int s = 1; s < 16; s <<= 1) mx = fmaxf(mx, __shfl_xor(mx, s, 64));
        float se = 0.0f;
        #pragma unroll
        for (int nf = 0; nf < 3; ++nf) {
            int col = nf * 16 + l15;
            if (col < OUT_CH) se += expf(v[nf] - mx);
        }
        #pragma unroll
        for (int s = 1; s < 16; s <<= 1) se += __shfl_xor(se, s, 64);
        float lz = mx + logf(se);
        if (row < N_NODES) {
            #pragma unroll
            for (int nf = 0; nf < 3; ++nf) {
                int col = nf * 16 + l15;
                if (col < OUT_CH)
                    out[(size_t)row * OUT_CH + col] = v[nf] - lz;
            }
        }
    }
}

// ---------------- launch ----------------
extern "C" void kernel_launch(void* const* d_in, const int* in_sizes, int n_in,
                              void* d_out, int out_size, void* d_ws, size_t ws_size,
                              hipStream_t stream) {
    const float* x   = (const float*)d_in[0];
    const void*  ei  = d_in[1];
    const float* W1l = (const float*)d_in[2];
    const float* b1  = (const float*)d_in[3];
    const float* W1r = (const float*)d_in[4];
    const float* W2l = (const float*)d_in[5];
    const float* b2  = (const float*)d_in[6];
    const float* W2r = (const float*)d_in[7];
    float* out = (float*)d_out;

    // ws layout (~94.7 MB)
    char* ws = (char*)d_ws;
    int*      flag   = (int*)ws;
    int*      gcnt   = (int*)(ws + 4096);                       // NB*16 ints, 64B-strided
    int*      bbase  = (int*)(ws + 106496);                     // 196 ints
    ushort*   x_bf   = (ushort*)(ws + 131072);                  // 25.6 MB
    ushort*   h_bf   = (ushort*)(ws + 131072 + 25600000);       // 25.6 MB
    ushort*   agg_bf = (ushort*)(ws + 131072 + 51200000);       // 25.6 MB
    ushort*   Wt1    = (ushort*)(ws + 131072 + 76800000);       // 64 KB
    ushort*   Wt2    = (ushort*)(ws + 131072 + 76865536);       // 24 KB
    uint2*    gbuf   = (uint2*)(ws + 77021184);                 // 16.06 MB (196*10240*8)
    uint32_t* dmask  = (uint32_t*)(ws + 93077504);              // 1.6 MB (end ~94.7 MB)

    // d_out (16 MB) doubles as CSR scratch; fully consumed before layer2 writes.
    char* ob = (char*)d_out;
    int* csr    = (int*)ob;                        // 6.4 MB
    int* cursor = (int*)(ob + 6400000);            // 400 KB

    prep<<<2, 256, 0, stream>>>((const int*)ei, flag, gcnt);
    bucket_edges<<<(N_EDGES + TILE_EDGES - 1) / TILE_EDGES, 256, 0, stream>>>(
        ei, flag, gcnt, gbuf);
    bucket_scan<<<1, 256, 0, stream>>>(gcnt, bbase);
    build_csr<<<NB, 256, 0, stream>>>(gcnt, gbuf, bbase, csr, cursor);

    cvt_and_mask<<<2048, 256, 0, stream>>>(x, x_bf, dmask);
    cvt_w2<<<176, 256, 0, stream>>>(W1l, W1r, W2l, W2r, Wt1, Wt2);

    aggregate_mean_bf<<<(N_NODES + 3) / 4, 256, 0, stream>>>(x_bf, csr, cursor, agg_bf);
    layer1_mfma<<<2 * ((N_NODES + 63) / 64), 256, 0, stream>>>(agg_bf, x_bf, Wt1, b1, dmask, h_bf);
    aggregate_mean_bf<<<(N_NODES + 3) / 4, 256, 0, stream>>>(h_bf, csr, cursor, agg_bf);
    layer2_mfma<<<(N_NODES + 63) / 64, 256, 0, stream>>>(agg_bf, h_bf, Wt2, b2, out);
}

// Round 15
// 271.693 us; speedup vs baseline: 1.2351x; 1.0785x over previous
//
#include <hip/hip_runtime.h>
#include <stdint.h>
#include <stddef.h>

#define N_NODES 100000
#define N_EDGES 1600000
#define IN_CH 128
#define HID_CH 128
#define OUT_CH 40

#define NB 196            // buckets: b = dst >> 9 (512 nodes each)
#define GCAP 10240        // per-bucket capacity (mean 8163 + 22 sigma)
#define TILE_EDGES 2048   // edges per WG in bucket_edges
#define LCAP 40           // LDS slots per bucket per tile

#define N_MASK_WORDS 400000   // 100000*128/32
#define N_CVT4 3200000        // 100000*128/4

#define WROW 264          // LDS row stride (ushorts) for K=256 tiles
#define WROW2 136         // LDS row stride (ushorts) for K=128 tiles

typedef __attribute__((ext_vector_type(8))) short bf16x8;
typedef __attribute__((ext_vector_type(8))) unsigned short u16x8;
typedef __attribute__((ext_vector_type(4))) float f32x4;

// ---------------- bf16 helpers ----------------
__device__ __forceinline__ ushort f2bf(float f) {
    uint32_t u = __float_as_uint(f);
    uint32_t r = (u + 0x7FFFu + ((u >> 16) & 1u)) >> 16;   // RNE
    return (ushort)r;
}
__device__ __forceinline__ float bf2f(ushort u) {
    return __uint_as_float(((uint32_t)u) << 16);
}

// ---------------- threefry2x32 (JAX PRNG, key = (0,42)) ----------------
__device__ __forceinline__ uint32_t rotl32(uint32_t x, int r) {
    return (x << r) | (x >> (32 - r));
}

__device__ __forceinline__ void threefry2x32_k42(uint32_t x0, uint32_t x1,
                                                 uint32_t& o0, uint32_t& o1) {
    const uint32_t ks0 = 0u, ks1 = 42u;
    const uint32_t ks2 = 0u ^ 42u ^ 0x1BD11BDAu;
    x0 += ks0; x1 += ks1;
    x0 += x1; x1 = rotl32(x1, 13); x1 ^= x0;
    x0 += x1; x1 = rotl32(x1, 15); x1 ^= x0;
    x0 += x1; x1 = rotl32(x1, 26); x1 ^= x0;
    x0 += x1; x1 = rotl32(x1,  6); x1 ^= x0;
    x0 += ks1; x1 += ks2 + 1u;
    x0 += x1; x1 = rotl32(x1, 17); x1 ^= x0;
    x0 += x1; x1 = rotl32(x1, 29); x1 ^= x0;
    x0 += x1; x1 = rotl32(x1, 16); x1 ^= x0;
    x0 += x1; x1 = rotl32(x1, 24); x1 ^= x0;
    x0 += ks2; x1 += ks0 + 2u;
    x0 += x1; x1 = rotl32(x1, 13); x1 ^= x0;
    x0 += x1; x1 = rotl32(x1, 15); x1 ^= x0;
    x0 += x1; x1 = rotl32(x1, 26); x1 ^= x0;
    x0 += x1; x1 = rotl32(x1,  6); x1 ^= x0;
    x0 += ks0; x1 += ks1 + 3u;
    x0 += x1; x1 = rotl32(x1, 17); x1 ^= x0;
    x0 += x1; x1 = rotl32(x1, 29); x1 ^= x0;
    x0 += x1; x1 = rotl32(x1, 16); x1 ^= x0;
    x0 += x1; x1 = rotl32(x1, 24); x1 ^= x0;
    x0 += ks1; x1 += ks2 + 4u;
    x0 += x1; x1 = rotl32(x1, 13); x1 ^= x0;
    x0 += x1; x1 = rotl32(x1, 15); x1 ^= x0;
    x0 += x1; x1 = rotl32(x1, 26); x1 ^= x0;
    x0 += x1; x1 = rotl32(x1,  6); x1 ^= x0;
    x0 += ks2; x1 += ks0 + 5u;
    o0 = x0; o1 = x1;
}

// ---------------- edge load ----------------
__device__ __forceinline__ void load_edge(const void* ei, bool is32, int e,
                                          int& s, int& d) {
    if (is32) {
        const int* p = (const int*)ei;
        s = p[e]; d = p[N_EDGES + e];
    } else {
        const long long* p = (const long long*)ei;
        s = (int)p[e]; d = (int)p[N_EDGES + e];
    }
}

// ---------------- prep: sampled dtype detect (block 0) + zero gcnt (block 1) --------
__global__ __launch_bounds__(256) void prep(const int* __restrict__ ei32,
                                            int* __restrict__ flag,
                                            int* __restrict__ gcnt) {
    const int t = threadIdx.x;
    if (blockIdx.x == 0) {
        __shared__ int red[256];
        int local = 0;
        #pragma unroll
        for (int j = 0; j < 64; ++j) {
            int k = (t * 64 + j) * 97;           // max 1,589,151 < N_EDGES
            local |= ei32[2 * k + 1];
        }
        red[t] = local;
        __syncthreads();
        for (int off = 128; off; off >>= 1) {
            if (t < off) red[t] |= red[t + off];
            __syncthreads();
        }
        if (t == 0) *flag = (red[0] != 0);
    } else {
        for (int i = t; i < NB * 16; i += 256) gcnt[i] = 0;
    }
}

// ---------------- bucketed CSR build, pass 1: LDS-staged append ----------------
__global__ __launch_bounds__(256) void bucket_edges(
    const void* __restrict__ ei, const int* __restrict__ flag,
    int* __restrict__ gcnt, uint2* __restrict__ gbuf) {
    __shared__ uint2 lbuf[NB][LCAP];   // 62.7 KB
    __shared__ int lcnt[NB];
    const bool is32 = (*flag != 0);
    const int t = threadIdx.x;
    for (int b = t; b < NB; b += 256) lcnt[b] = 0;
    __syncthreads();
    const int base = blockIdx.x * TILE_EDGES;
    #pragma unroll
    for (int j = 0; j < TILE_EDGES / 256; ++j) {
        int e = base + j * 256 + t;
        if (e < N_EDGES) {
            int s, d;
            load_edge(ei, is32, e, s, d);
            int b = d >> 9;
            int pos = atomicAdd(&lcnt[b], 1);
            if (pos < LCAP) {
                lbuf[b][pos] = make_uint2((uint32_t)s, (uint32_t)d);
            } else {   // overflow slow path (statistically ~never)
                int gp = atomicAdd(&gcnt[b * 16], 1);
                gbuf[(size_t)b * GCAP + gp] = make_uint2((uint32_t)s, (uint32_t)d);
            }
        }
    }
    __syncthreads();
    if (t < NB) {
        int cnt = lcnt[t];
        if (cnt > LCAP) cnt = LCAP;
        if (cnt > 0) {
            int gp = atomicAdd(&gcnt[t * 16], cnt);
            uint2* dst = gbuf + (size_t)t * GCAP + gp;
            for (int i = 0; i < cnt; ++i) dst[i] = lbuf[t][i];
        }
    }
}

// exclusive scan of bucket totals (196 values, 1 block)
__global__ void bucket_scan(const int* __restrict__ gcnt, int* __restrict__ bbase) {
    __shared__ int s[256];
    int t = threadIdx.x;
    int tot = (t < NB) ? gcnt[t * 16] : 0;
    s[t] = tot;
    __syncthreads();
    for (int off = 1; off < 256; off <<= 1) {
        int a = (t >= off) ? s[t - off] : 0;
        __syncthreads();
        s[t] += a;
        __syncthreads();
    }
    if (t < NB) bbase[t] = s[t] - tot;   // exclusive
}

// pass 2: one WG per bucket -> exact degrees (histogram), scan, cursor, place.
__global__ __launch_bounds__(256) void build_csr(
    const int* __restrict__ gcnt, const uint2* __restrict__ gbuf,
    const int* __restrict__ bbase, int* __restrict__ csr, int* __restrict__ cursor) {
    __shared__ int hist[512];
    __shared__ int excl[512];
    __shared__ int cur[512];
    __shared__ int psum[256];
    const int b = blockIdx.x;
    const int t = threadIdx.x;
    hist[t] = 0; hist[t + 256] = 0;
    __syncthreads();
    const int base = bbase[b];
    const int cnt = gcnt[b * 16];
    const uint2* src = gbuf + (size_t)b * GCAP;
    for (int i = t; i < cnt; i += 256)
        atomicAdd(&hist[src[i].y & 511], 1);
    __syncthreads();
    int h0 = hist[2 * t], h1 = hist[2 * t + 1];
    psum[t] = h0 + h1;
    __syncthreads();
    int v = psum[t];
    for (int off = 1; off < 256; off <<= 1) {
        int a = (t >= off) ? psum[t - off] : 0;
        __syncthreads();
        psum[t] += a;
        __syncthreads();
    }
    int pex = psum[t] - v;
    excl[2 * t] = pex;
    excl[2 * t + 1] = pex + h0;
    cur[2 * t] = pex;
    cur[2 * t + 1] = pex + h0;
    __syncthreads();
    for (int j = t; j < 512; j += 256) {
        int node = b * 512 + j;
        if (node < N_NODES) cursor[node] = base + excl[j] + hist[j];
    }
    for (int i = t; i < cnt; i += 256) {
        uint2 p = src[i];
        int pos = atomicAdd(&cur[p.y & 511], 1);
        csr[base + pos] = (int)p.x;
    }
}

// ---------------- fused: x -> bf16 conversion + dropout mask precompute ----------------
__global__ __launch_bounds__(256) void cvt_and_mask(
    const float* __restrict__ in, ushort* __restrict__ out,
    uint32_t* __restrict__ mask) {
    const long gid = (long)blockIdx.x * blockDim.x + threadIdx.x;
    const long stride = (long)gridDim.x * blockDim.x;
    for (long i = gid; i < N_CVT4; i += stride) {
        float4 v = *reinterpret_cast<const float4*>(in + i * 4);
        ushort4 r;
        r.x = f2bf(v.x); r.y = f2bf(v.y); r.z = f2bf(v.z); r.w = f2bf(v.w);
        *reinterpret_cast<ushort4*>(out + i * 4) = r;
    }
    for (long w = gid; w < N_MASK_WORDS; w += stride) {
        uint32_t m = 0;
        #pragma unroll 4
        for (int j = 0; j < 32; ++j) {
            uint32_t o0, o1;
            threefry2x32_k42(0u, (uint32_t)w * 32u + j, o0, o1);
            m |= ((o0 ^ o1) >> 31) << j;
        }
        mask[w] = m;
    }
}

// Wt1[n*256 + k] = bf16(k<128 ? W1l[k][n] : W1r[k-128][n])      (128 cols, K=256)
// Wt2[n*128 + k] = bf16(n<40 ? W2l[k][n] : W2r[k][n-40])        (80 cols,  K=128)
__global__ void cvt_w2(const float* __restrict__ W1l, const float* __restrict__ W1r,
                       const float* __restrict__ W2l, const float* __restrict__ W2r,
                       ushort* __restrict__ Wt1, ushort* __restrict__ Wt2) {
    int blk = blockIdx.x;
    int k = threadIdx.x;
    if (blk < 128) {
        int n = blk;
        float v = (k < 128) ? W1l[(size_t)k * 128 + n] : W1r[(size_t)(k - 128) * 128 + n];
        Wt1[(size_t)n * 256 + k] = f2bf(v);
    } else if (k < 128) {
        int n = blk - 128;   // 0..79
        float v = (n < OUT_CH) ? W2l[(size_t)k * 40 + n]
                               : W2r[(size_t)k * 40 + (n - OUT_CH)];
        Wt2[(size_t)n * 128 + k] = f2bf(v);
    }
}

// ---------------- x-aggregate (128-wide, uniform csr-prefetch + shfl) --------
__global__ __launch_bounds__(256) void aggregate_mean_bf(
    const ushort* __restrict__ feat, const int* __restrict__ csr,
    const int* __restrict__ cursor, ushort* __restrict__ out) {
    int node = blockIdx.x * 4 + (threadIdx.x >> 6);
    if (node >= N_NODES) return;
    const int lane = threadIdx.x & 63;
    const int g = lane >> 4;        // 0..3 edge subgroup
    const int c = lane & 15;        // col group: channels c*8..c*8+7
    const int beg = (node > 0) ? cursor[node - 1] : 0;
    const int end = cursor[node];
    const int deg = end - beg;

    int myidx = (lane < deg) ? csr[beg + lane] : 0;

    float acc[8];
    #pragma unroll
    for (int j = 0; j < 8; ++j) acc[j] = 0.0f;

    const int nfull = (deg < 64) ? deg : 64;
    const int niter = (nfull + 3) >> 2;   // wave-uniform trip count
    #pragma unroll 4
    for (int k = 0; k < niter; ++k) {
        int e = g + 4 * k;
        bool valid = (e < nfull);
        int es = valid ? e : 0;
        int s = __shfl(myidx, es, 64);
        float w = valid ? 1.0f : 0.0f;
        bf16x8 v = *reinterpret_cast<const bf16x8*>(feat + (size_t)s * 128 + c * 8);
        #pragma unroll
        for (int j = 0; j < 8; ++j) acc[j] += w * bf2f((ushort)v[j]);
    }
    for (int e = 64 + g; e < deg; e += 4) {
        int s = csr[beg + e];
        bf16x8 v = *reinterpret_cast<const bf16x8*>(feat + (size_t)s * 128 + c * 8);
        #pragma unroll
        for (int j = 0; j < 8; ++j) acc[j] += bf2f((ushort)v[j]);
    }

    #pragma unroll
    for (int j = 0; j < 8; ++j) {
        acc[j] += __shfl_xor(acc[j], 16, 64);
        acc[j] += __shfl_xor(acc[j], 32, 64);
    }

    if (g == 0) {
        float inv = (deg > 0) ? (1.0f / (float)deg) : 0.0f;
        u16x8 r;
        #pragma unroll
        for (int j = 0; j < 8; ++j) r[j] = f2bf(acc[j] * inv);
        *reinterpret_cast<u16x8*>(out + (size_t)node * 128 + c * 8) = r;
    }
}

// ---------------- layer 1 MFMA (LDS-staged weights) ----------------
__global__ __launch_bounds__(256) void layer1_mfma(
    const ushort* __restrict__ agg, const ushort* __restrict__ xbf,
    const ushort* __restrict__ Wt, const float* __restrict__ b1,
    const uint32_t* __restrict__ dmask, ushort* __restrict__ h) {
    __shared__ ushort wlds[64 * WROW];   // 33.8 KB
    const int tid = threadIdx.x;
    const int lane = tid & 63;
    const int l15 = lane & 15, kg = lane >> 4;
    const int colBase = (blockIdx.x & 1) * 64;
    const int row_base = ((blockIdx.x >> 1) * 4 + (tid >> 6)) * 16;

    #pragma unroll
    for (int i = 0; i < 8; ++i) {
        int idx = tid + i * 256;
        int r = idx >> 5, c = idx & 31;
        u16x8 v = *reinterpret_cast<const u16x8*>(Wt + (size_t)(colBase + r) * 256 + c * 8);
        *reinterpret_cast<u16x8*>(wlds + r * WROW + c * 8) = v;
    }
    __syncthreads();
    if (row_base >= N_NODES) return;

    int r0 = row_base + l15;
    int r0c = (r0 < N_NODES) ? r0 : (N_NODES - 1);

    bf16x8 a[8];
    #pragma unroll
    for (int ks = 0; ks < 4; ++ks) {
        a[ks]     = *reinterpret_cast<const bf16x8*>(agg + (size_t)r0c * 128 + ks * 32 + kg * 8);
        a[ks + 4] = *reinterpret_cast<const bf16x8*>(xbf + (size_t)r0c * 128 + ks * 32 + kg * 8);
    }

    f32x4 acc[4];
    #pragma unroll
    for (int nf = 0; nf < 4; ++nf) acc[nf] = (f32x4){0.f, 0.f, 0.f, 0.f};

    #pragma unroll
    for (int nf = 0; nf < 4; ++nf) {
        const ushort* bp = wlds + (nf * 16 + l15) * WROW + kg * 8;
        #pragma unroll
        for (int ks = 0; ks < 8; ++ks) {
            bf16x8 b = *reinterpret_cast<const bf16x8*>(bp + ks * 32);
            acc[nf] = __builtin_amdgcn_mfma_f32_16x16x32_bf16(a[ks], b, acc[nf], 0, 0, 0);
        }
    }

    #pragma unroll
    for (int r = 0; r < 4; ++r) {
        int row = row_base + kg * 4 + r;
        if (row < N_NODES) {
            uint4 mw = *reinterpret_cast<const uint4*>(dmask + (size_t)row * 4);
            const uint32_t* mwp = reinterpret_cast<const uint32_t*>(&mw);
            #pragma unroll
            for (int nf = 0; nf < 4; ++nf) {
                int col = colBase + nf * 16 + l15;
                float v = acc[nf][r] + b1[col];
                v = fmaxf(v, 0.0f) * 2.0f;
                if ((mwp[col >> 5] >> (col & 31)) & 1u) v = 0.0f;
                h[(size_t)row * 128 + col] = f2bf(v);
            }
        }
    }
}

// ---------------- layer2_pre: y2z2 = h @ [W2l|W2r] (K=128, 80 cols, bf16 out) ----------
__global__ __launch_bounds__(256) void layer2_pre(
    const ushort* __restrict__ hbf, const ushort* __restrict__ Wt2,
    ushort* __restrict__ y2z2) {
    __shared__ ushort wlds[80 * WROW2];   // 21.3 KB
    const int tid = threadIdx.x;
    const int lane = tid & 63;
    const int l15 = lane & 15, kg = lane >> 4;
    const int row_base = (blockIdx.x * 4 + (tid >> 6)) * 16;

    // stage 80 cols x 128 k (1280 16B chunks, 5 per thread)
    #pragma unroll
    for (int i = 0; i < 5; ++i) {
        int idx = tid + i * 256;
        int r = idx >> 4, c = idx & 15;
        u16x8 v = *reinterpret_cast<const u16x8*>(Wt2 + (size_t)r * 128 + c * 8);
        *reinterpret_cast<u16x8*>(wlds + r * WROW2 + c * 8) = v;
    }
    __syncthreads();
    if (row_base >= N_NODES) return;

    int r0 = row_base + l15;
    int r0c = (r0 < N_NODES) ? r0 : (N_NODES - 1);

    bf16x8 a[4];
    #pragma unroll
    for (int ks = 0; ks < 4; ++ks)
        a[ks] = *reinterpret_cast<const bf16x8*>(hbf + (size_t)r0c * 128 + ks * 32 + kg * 8);

    f32x4 acc[5];
    #pragma unroll
    for (int nf = 0; nf < 5; ++nf) acc[nf] = (f32x4){0.f, 0.f, 0.f, 0.f};

    #pragma unroll
    for (int nf = 0; nf < 5; ++nf) {
        const ushort* bp = wlds + (nf * 16 + l15) * WROW2 + kg * 8;
        #pragma unroll
        for (int ks = 0; ks < 4; ++ks) {
            bf16x8 b = *reinterpret_cast<const bf16x8*>(bp + ks * 32);
            acc[nf] = __builtin_amdgcn_mfma_f32_16x16x32_bf16(a[ks], b, acc[nf], 0, 0, 0);
        }
    }

    #pragma unroll
    for (int r = 0; r < 4; ++r) {
        int row = row_base + kg * 4 + r;
        if (row < N_NODES) {
            #pragma unroll
            for (int nf = 0; nf < 5; ++nf) {
                int col = nf * 16 + l15;   // 0..79, all valid
                y2z2[(size_t)row * 80 + col] = f2bf(acc[nf][r]);
            }
        }
    }
}

// ---------------- 40-wide aggregate: aggy2 = segment_mean(y2[src]) --------------------
// One wave per node: 8 edge subgroups (g = lane>>3) x 8 ch-slots (c = lane&7).
// Only c<5 carry data (40 ch); c>=5 duplicate c-5's address with w=0 (coalesced away).
// Wave-uniform loop + clamped shfl (R13 discipline).  Reduce over g: xor 8/16/32.
__global__ __launch_bounds__(256) void aggregate_mean_40(
    const ushort* __restrict__ y2, const int* __restrict__ csr,
    const int* __restrict__ cursor, ushort* __restrict__ aggy2) {
    int node = blockIdx.x * 4 + (threadIdx.x >> 6);
    if (node >= N_NODES) return;
    const int lane = threadIdx.x & 63;
    const int g = lane >> 3;        // 0..7 edge subgroup
    const int c = lane & 7;         // ch slot
    const int cc = (c < 5) ? c : (c - 5);
    const float cw = (c < 5) ? 1.0f : 0.0f;
    const int beg = (node > 0) ? cursor[node - 1] : 0;
    const int end = cursor[node];
    const int deg = end - beg;

    int myidx = (lane < deg) ? csr[beg + lane] : 0;

    float acc[8];
    #pragma unroll
    for (int j = 0; j < 8; ++j) acc[j] = 0.0f;

    const int nfull = (deg < 64) ? deg : 64;
    const int niter = (nfull + 7) >> 3;   // wave-uniform
    for (int k = 0; k < niter; ++k) {
        int e = g + 8 * k;
        bool valid = (e < nfull);
        int es = valid ? e : 0;
        int s = __shfl(myidx, es, 64);
        float w = valid ? cw : 0.0f;
        bf16x8 v = *reinterpret_cast<const bf16x8*>(y2 + (size_t)s * 80 + cc * 8);
        #pragma unroll
        for (int j = 0; j < 8; ++j) acc[j] += w * bf2f((ushort)v[j]);
    }
    for (int e = 64 + g; e < deg; e += 8) {
        int s = csr[beg + e];
        bf16x8 v = *reinterpret_cast<const bf16x8*>(y2 + (size_t)s * 80 + cc * 8);
        #pragma unroll
        for (int j = 0; j < 8; ++j) acc[j] += cw * bf2f((ushort)v[j]);
    }

    // reduce across the 8 edge subgroups (g = lane bits 3..5)
    #pragma unroll
    for (int j = 0; j < 8; ++j) {
        acc[j] += __shfl_xor(acc[j], 8, 64);
        acc[j] += __shfl_xor(acc[j], 16, 64);
        acc[j] += __shfl_xor(acc[j], 32, 64);
    }

    if (lane < 5) {   // g==0, c==0..4
        float inv = (deg > 0) ? (1.0f / (float)deg) : 0.0f;
        u16x8 r;
        #pragma unroll
        for (int j = 0; j < 8; ++j) r[j] = f2bf(acc[j] * inv);
        *reinterpret_cast<u16x8*>(aggy2 + (size_t)node * 40 + lane * 8) = r;
    }
}

// ---------------- layer2_post: out = log_softmax(aggy2 + z2 + b2) --------------------
__global__ __launch_bounds__(256) void layer2_post(
    const ushort* __restrict__ aggy2, const ushort* __restrict__ y2z2,
    const float* __restrict__ b2, float* __restrict__ out) {
    int node = blockIdx.x * blockDim.x + threadIdx.x;
    if (node >= N_NODES) return;

    float v[40];
    #pragma unroll
    for (int i = 0; i < 5; ++i) {
        u16x8 av = *reinterpret_cast<const u16x8*>(aggy2 + (size_t)node * 40 + i * 8);
        u16x8 zv = *reinterpret_cast<const u16x8*>(y2z2 + (size_t)node * 80 + 40 + i * 8);
        #pragma unroll
        for (int j = 0; j < 8; ++j)
            v[i * 8 + j] = bf2f((ushort)av[j]) + bf2f((ushort)zv[j]) + b2[i * 8 + j];
    }
    float mx = -1e30f;
    #pragma unroll
    for (int j = 0; j < 40; ++j) mx = fmaxf(mx, v[j]);
    float se = 0.0f;
    #pragma unroll
    for (int j = 0; j < 40; ++j) se += expf(v[j] - mx);
    float lz = mx + logf(se);
    #pragma unroll
    for (int i = 0; i < 10; ++i) {
        float4 r;
        r.x = v[i * 4 + 0] - lz;
        r.y = v[i * 4 + 1] - lz;
        r.z = v[i * 4 + 2] - lz;
        r.w = v[i * 4 + 3] - lz;
        *reinterpret_cast<float4*>(out + (size_t)node * 40 + i * 4) = r;
    }
}

// ---------------- launch ----------------
extern "C" void kernel_launch(void* const* d_in, const int* in_sizes, int n_in,
                              void* d_out, int out_size, void* d_ws, size_t ws_size,
                              hipStream_t stream) {
    const float* x   = (const float*)d_in[0];
    const void*  ei  = d_in[1];
    const float* W1l = (const float*)d_in[2];
    const float* b1  = (const float*)d_in[3];
    const float* W1r = (const float*)d_in[4];
    const float* W2l = (const float*)d_in[5];
    const float* b2  = (const float*)d_in[6];
    const float* W2r = (const float*)d_in[7];
    float* out = (float*)d_out;

    // ws layout (~94.7 MB)
    char* ws = (char*)d_ws;
    int*      flag   = (int*)ws;
    int*      gcnt   = (int*)(ws + 4096);
    int*      bbase  = (int*)(ws + 106496);
    ushort*   x_bf   = (ushort*)(ws + 131072);                  // 25.6 MB
    ushort*   h_bf   = (ushort*)(ws + 131072 + 25600000);       // 25.6 MB
    ushort*   agg_bf = (ushort*)(ws + 131072 + 51200000);       // 25.6 MB (x-agg; dead after layer1)
    ushort*   Wt1    = (ushort*)(ws + 131072 + 76800000);       // 64 KB
    ushort*   Wt2    = (ushort*)(ws + 131072 + 76865536);       // 20.5 KB (80x128)
    uint2*    gbuf   = (uint2*)(ws + 77021184);                 // 16.06 MB
    uint32_t* dmask  = (uint32_t*)(ws + 93077504);              // 1.6 MB

    // reuse agg_bf region after layer1: y2z2 (16 MB) + aggy2 (8 MB) < 25.6 MB
    ushort* y2z2  = (ushort*)(ws + 131072 + 51200000);
    ushort* aggy2 = (ushort*)(ws + 131072 + 51200000 + 16000000);

    // d_out doubles as CSR scratch; last consumer is aggregate_mean_40, then
    // layer2_post overwrites d_out with the real output (stream-ordered).
    char* ob = (char*)d_out;
    int* csr    = (int*)ob;                        // 6.4 MB
    int* cursor = (int*)(ob + 6400000);            // 400 KB

    prep<<<2, 256, 0, stream>>>((const int*)ei, flag, gcnt);
    bucket_edges<<<(N_EDGES + TILE_EDGES - 1) / TILE_EDGES, 256, 0, stream>>>(
        ei, flag, gcnt, gbuf);
    bucket_scan<<<1, 256, 0, stream>>>(gcnt, bbase);
    build_csr<<<NB, 256, 0, stream>>>(gcnt, gbuf, bbase, csr, cursor);

    cvt_and_mask<<<2048, 256, 0, stream>>>(x, x_bf, dmask);
    cvt_w2<<<208, 256, 0, stream>>>(W1l, W1r, W2l, W2r, Wt1, Wt2);

    aggregate_mean_bf<<<(N_NODES + 3) / 4, 256, 0, stream>>>(x_bf, csr, cursor, agg_bf);
    layer1_mfma<<<2 * ((N_NODES + 63) / 64), 256, 0, stream>>>(agg_bf, x_bf, Wt1, b1, dmask, h_bf);

    layer2_pre<<<(N_NODES + 63) / 64, 256, 0, stream>>>(h_bf, Wt2, y2z2);
    aggregate_mean_40<<<(N_NODES + 3) / 4, 256, 0, stream>>>(y2z2, csr, cursor, aggy2);
    layer2_post<<<(N_NODES + 255) / 256, 256, 0, stream>>>(aggy2, y2z2, b2, out);
}